// Round 2
// baseline (536.124 us; speedup 1.0000x reference)
//
#include <hip/hip_runtime.h>

typedef __bf16 bf16;
typedef __bf16 bf16x8 __attribute__((ext_vector_type(8)));
typedef float f32x4 __attribute__((ext_vector_type(4)));

#define B_ 2
#define S_ 2048
#define D_ 2048
#define H_ 16
#define HKV_ 4
#define HD_ 128
#define QKVW 3072
#define SCALE 0.08838834764831845f  // 1/sqrt(128)
#define NEGINF -30000.0f            // finite "minus infinity": exp() underflows to 0, no inf-inf

// ---------------- dtype detection: are the float tensors bf16 or fp32? ----------------
// Sample 256 u32 words of x. In a bf16 world the low half-word is a bf16 of ~N(0,1)
// data -> exponent field in [100,140] (or exact zero) ~always. In an fp32 world the low
// half is uniform mantissa bits -> ~16% hit that range. Vote threshold 128.
__global__ void detect_dtype(const unsigned* __restrict__ xw, int* __restrict__ flag) {
  __shared__ int cnt;
  if (threadIdx.x == 0) cnt = 0;
  __syncthreads();
  unsigned w = xw[(size_t)threadIdx.x * 16384];  // max idx 255*16384 < 4194304 (bf16-world words)
  unsigned low = w & 0xFFFFu;
  int e = (int)((low >> 7) & 0xFF);
  int vote = (low == 0u || (e >= 100 && e <= 140)) ? 1 : 0;
  atomicAdd(&cnt, vote);
  __syncthreads();
  if (threadIdx.x == 0) *flag = (cnt >= 128) ? 1 : 0;  // 1 = bf16 inputs, 0 = fp32 inputs
}

// ---------------- x -> bf16 (copy or convert), 8 elems/thread ----------------
__global__ __launch_bounds__(256) void convert_x(const void* __restrict__ in,
                                                 bf16* __restrict__ out,
                                                 const int* __restrict__ flag, int n8) {
  int fm = *flag;
  int i = blockIdx.x * 256 + threadIdx.x;
  if (i >= n8) return;
  if (fm) {
    ((uint4*)out)[i] = ((const uint4*)in)[i];
  } else {
    const float* fin = (const float*)in + (long)i * 8;
    alignas(16) bf16 tmp[8];
#pragma unroll
    for (int j = 0; j < 8; j++) tmp[j] = (bf16)fin[j];
    ((uint4*)out)[i] = *(const uint4*)tmp;
  }
}

// ---------------- tiled transpose (+ optional fp32->bf16 convert): out[c][r] = in[r][c] ----
// flag==nullptr -> input is bf16 (internal tensors). Grid must exactly cover (cols/32, rows/32, batch).
__global__ __launch_bounds__(256) void transpose_cvt(
    const void* __restrict__ in, bf16* __restrict__ out,
    long in_stride, long out_stride, long in_bstride, long out_bstride,
    const int* __restrict__ flag) {
  __shared__ float tile[32][33];
  int fm = flag ? *flag : 1;
  long ib = (long)blockIdx.z * in_bstride;
  long ob = (long)blockIdx.z * out_bstride;
  int c0 = blockIdx.x * 32;
  int r0 = blockIdx.y * 32;
  int tx = threadIdx.x, ty = threadIdx.y;  // 32 x 8
#pragma unroll
  for (int i = 0; i < 32; i += 8) {
    long idx = ib + (long)(r0 + ty + i) * in_stride + c0 + tx;
    tile[ty + i][tx] = fm ? (float)((const bf16*)in)[idx] : ((const float*)in)[idx];
  }
  __syncthreads();
#pragma unroll
  for (int i = 0; i < 32; i += 8)
    out[ob + (long)(c0 + ty + i) * out_stride + r0 + tx] = (bf16)tile[tx][ty + i];
}

// ---------------- GEMM: C[M,N] = A[M,K] * Bt[N,K]^T, bf16 in, fp32 acc ----------------
// Output dtype: bf16 if (flag==nullptr || *flag), else fp32.
#define BM 128
#define BN 128
#define BK 32
#define LDST 56  // lds row stride (bf16 elems): 112B, 16B-aligned, 2-way bank alias (free)

__global__ __launch_bounds__(256) void gemm_bt(
    const bf16* __restrict__ A, const bf16* __restrict__ Bt,
    void* __restrict__ C, int M, int N, int K, const int* __restrict__ flag) {
  alignas(16) __shared__ bf16 la[BM * LDST];
  alignas(16) __shared__ bf16 lb[BN * LDST];
  int fm = flag ? *flag : 1;
  int tid = threadIdx.x;
  int wave = tid >> 6, lane = tid & 63;
  int wr = wave >> 1, wc = wave & 1;
  int quad = lane >> 4, l16 = lane & 15;
  int m0 = blockIdx.y * BM, n0 = blockIdx.x * BN;

  f32x4 acc[4][4] = {};

  int srow = tid >> 1;        // 0..127
  int skh = (tid & 1) * 16;   // 0 / 16
  const uint4* ga = (const uint4*)(A + (long)(m0 + srow) * K + skh);
  const uint4* gb = (const uint4*)(Bt + (long)(n0 + srow) * K + skh);
  uint4* wa = (uint4*)(la + srow * LDST + skh);
  uint4* wb = (uint4*)(lb + srow * LDST + skh);

  for (int k0 = 0; k0 < K; k0 += BK) {
    uint4 a0 = ga[0], a1 = ga[1];
    uint4 b0 = gb[0], b1 = gb[1];
    ga += BK / 8; gb += BK / 8;
    __syncthreads();
    wa[0] = a0; wa[1] = a1;
    wb[0] = b0; wb[1] = b1;
    __syncthreads();

    const bf16* pa = la + (wr * 64 + l16) * LDST + quad * 8;
    const bf16* pb = lb + (wc * 64 + l16) * LDST + quad * 8;
    bf16x8 af[4], bfr[4];
#pragma unroll
    for (int i = 0; i < 4; i++) af[i] = *(const bf16x8*)(pa + i * 16 * LDST);
#pragma unroll
    for (int j = 0; j < 4; j++) bfr[j] = *(const bf16x8*)(pb + j * 16 * LDST);
#pragma unroll
    for (int i = 0; i < 4; i++)
#pragma unroll
      for (int j = 0; j < 4; j++)
        acc[i][j] = __builtin_amdgcn_mfma_f32_16x16x32_bf16(af[i], bfr[j], acc[i][j], 0, 0, 0);
  }

  // C/D layout: col = lane&15, row = quad*4 + reg   [m89/m91-verified]
#pragma unroll
  for (int i = 0; i < 4; i++)
#pragma unroll
    for (int j = 0; j < 4; j++)
#pragma unroll
      for (int r = 0; r < 4; r++) {
        long row = m0 + wr * 64 + i * 16 + quad * 4 + r;
        long col = n0 + wc * 64 + j * 16 + l16;
        float v = acc[i][j][r];
        if (fm) ((bf16*)C)[row * N + col] = (bf16)v;
        else    ((float*)C)[row * N + col] = v;
      }
}

// ---------------- RoPE + scatter: qkv row -> Q[b,h,s,hd], K[b,kh,s,hd] ----------------
__global__ __launch_bounds__(256) void rope_scatter(
    const bf16* __restrict__ qkv, bf16* __restrict__ Q, bf16* __restrict__ Ko) {
  int row = blockIdx.x;  // b*S + s
  int b = row >> 11, s = row & 2047;
  int tid = threadIdx.x;
  const bf16* src = qkv + (long)row * QKVW;
#pragma unroll
  for (int it = 0; it < 4; ++it) {
    int p = tid + it * 256;
    int h = p >> 6, i = p & 63;
    float x1 = (float)src[h * 128 + 2 * i];
    float x2 = (float)src[h * 128 + 2 * i + 1];
    float theta = __expf(-0.14391156831212787f * (float)i);  // 10000^(-2i/128)
    float sn, cs;
    sincosf((float)s * theta, &sn, &cs);
    long qb = ((long)(b * H_ + h) * S_ + s) * HD_;
    Q[qb + i] = (bf16)(x1 * cs - x2 * sn);
    Q[qb + 64 + i] = (bf16)(x1 * sn + x2 * cs);
  }
  {
    int kh = tid >> 6, i = tid & 63;
    float x1 = (float)src[2048 + kh * 128 + 2 * i];
    float x2 = (float)src[2048 + kh * 128 + 2 * i + 1];
    float theta = __expf(-0.14391156831212787f * (float)i);
    float sn, cs;
    sincosf((float)s * theta, &sn, &cs);
    long kb = ((long)(b * HKV_ + kh) * S_ + s) * HD_;
    Ko[kb + i] = (bf16)(x1 * cs - x2 * sn);
    Ko[kb + 64 + i] = (bf16)(x1 * sn + x2 * cs);
  }
}

// ---------------- flash attention, causal, 64-row Q tiles ----------------
#define QSTR 136  // 128-wide tiles: 272B stride, 16B-aligned, 2-way alias
#define VSTR 72   // 64-wide tiles: 144B stride
#define PSTR 72

__global__ __launch_bounds__(256) void attn_kernel(
    const bf16* __restrict__ Q, const bf16* __restrict__ K,
    const bf16* __restrict__ Vt, bf16* __restrict__ O) {
  alignas(16) __shared__ bf16 Qs[64 * QSTR];
  alignas(16) __shared__ bf16 Ks[64 * QSTR];
  alignas(16) __shared__ bf16 Vs[128 * VSTR];
  alignas(16) __shared__ bf16 Ps[64 * PSTR];
  int qt = blockIdx.x, h = blockIdx.y, b = blockIdx.z;
  int kh = h >> 2;  // GQA: rep=4
  int tid = threadIdx.x, wave = tid >> 6, lane = tid & 63;
  int quad = lane >> 4, l16 = lane & 15;
  int q0 = qt * 64;
  const bf16* Qg = Q + ((long)(b * H_ + h) * S_ + q0) * HD_;
  const bf16* Kg = K + ((long)(b * HKV_ + kh) * S_) * HD_;
  const bf16* Vg = Vt + ((long)(b * HKV_ + kh) * HD_) * S_;

  {  // stage Q tile (64 x 128)
    int r = tid >> 2, c = (tid & 3) * 32;
    const uint4* g = (const uint4*)(Qg + r * HD_ + c);
    uint4* d = (uint4*)(Qs + r * QSTR + c);
    d[0] = g[0]; d[1] = g[1]; d[2] = g[2]; d[3] = g[3];
  }

  f32x4 Of[8] = {};
  float m_run[4], l_run[4];
#pragma unroll
  for (int r = 0; r < 4; r++) { m_run[r] = NEGINF; l_run[r] = 0.f; }

  for (int kt = 0; kt <= qt; ++kt) {
    __syncthreads();  // protect Ks/Vs/Ps against prior-iter readers
    {  // stage K tile (64 x 128)
      int r = tid >> 2, c = (tid & 3) * 32;
      const uint4* g = (const uint4*)(Kg + (long)(kt * 64 + r) * HD_ + c);
      uint4* d = (uint4*)(Ks + r * QSTR + c);
      d[0] = g[0]; d[1] = g[1]; d[2] = g[2]; d[3] = g[3];
    }
    {  // stage V^T tile (128 hd x 64 s)
      int r = tid >> 1, c = (tid & 1) * 32;
      const uint4* g = (const uint4*)(Vg + (long)r * S_ + kt * 64 + c);
      uint4* d = (uint4*)(Vs + r * VSTR + c);
      d[0] = g[0]; d[1] = g[1]; d[2] = g[2]; d[3] = g[3];
    }
    __syncthreads();

    // S = Q K^T for this wave's 16 q-rows x 64 k-cols
    f32x4 sf[4];
    const bf16* pq = Qs + (wave * 16 + l16) * QSTR + quad * 8;
#pragma unroll
    for (int j = 0; j < 4; j++) {
      f32x4 a = {};
#pragma unroll
      for (int kk = 0; kk < 4; kk++) {
        bf16x8 qa = *(const bf16x8*)(pq + kk * 32);
        bf16x8 kb = *(const bf16x8*)(Ks + (j * 16 + l16) * QSTR + kk * 32 + quad * 8);
        a = __builtin_amdgcn_mfma_f32_16x16x32_bf16(qa, kb, a, 0, 0, 0);
      }
      sf[j] = a;
    }

    // online softmax per row (row = wave*16 + quad*4 + r, owned by 16 lanes of the quad)
#pragma unroll
    for (int r = 0; r < 4; r++) {
      int grow = q0 + wave * 16 + quad * 4 + r;
      float sv[4];
      float mx = NEGINF;
#pragma unroll
      for (int j = 0; j < 4; j++) {
        float v = sf[j][r] * SCALE;
        int gcol = kt * 64 + j * 16 + l16;
        if (gcol > grow) v = NEGINF;  // causal
        sv[j] = v;
        mx = fmaxf(mx, v);
      }
#pragma unroll
      for (int off = 1; off < 16; off <<= 1) mx = fmaxf(mx, __shfl_xor(mx, off));
      float mnew = fmaxf(m_run[r], mx);
      float alpha = __expf(m_run[r] - mnew);
      float rs = 0.f;
#pragma unroll
      for (int j = 0; j < 4; j++) {
        float p = __expf(sv[j] - mnew);
        rs += p;
        Ps[(wave * 16 + quad * 4 + r) * PSTR + j * 16 + l16] = (bf16)p;
      }
#pragma unroll
      for (int off = 1; off < 16; off <<= 1) rs += __shfl_xor(rs, off);
      l_run[r] = l_run[r] * alpha + rs;
      m_run[r] = mnew;
#pragma unroll
      for (int n = 0; n < 8; n++) Of[n][r] *= alpha;
    }
    __syncthreads();  // P visible before PV

    // O += P V : P as A-operand from LDS, V^T rows give B-frags
    const bf16* pp = Ps + (wave * 16 + l16) * PSTR + quad * 8;
#pragma unroll
    for (int kk = 0; kk < 2; kk++) {
      bf16x8 pa = *(const bf16x8*)(pp + kk * 32);
#pragma unroll
      for (int n = 0; n < 8; n++) {
        bf16x8 vb = *(const bf16x8*)(Vs + (n * 16 + l16) * VSTR + kk * 32 + quad * 8);
        Of[n] = __builtin_amdgcn_mfma_f32_16x16x32_bf16(pa, vb, Of[n], 0, 0, 0);
      }
    }
  }

  // epilogue: O /= l, write attno[b, s, h*128 + hd]
#pragma unroll
  for (int r = 0; r < 4; r++) {
    int grow = q0 + wave * 16 + quad * 4 + r;
    float inv = 1.0f / fmaxf(l_run[r], 1e-30f);
#pragma unroll
    for (int n = 0; n < 8; n++)
      O[((long)(b * S_) + grow) * D_ + h * HD_ + n * 16 + l16] = (bf16)(Of[n][r] * inv);
  }
}

// ---------------- launch ----------------
extern "C" void kernel_launch(void* const* d_in, const int* in_sizes, int n_in,
                              void* d_out, int out_size, void* d_ws, size_t ws_size,
                              hipStream_t stream) {
  const void* x  = d_in[0];
  const void* Wq = d_in[1];
  const void* Wk = d_in[2];
  const void* Wv = d_in[3];
  const void* Wo = d_in[4];
  bf16* ws = (bf16*)d_ws;
  int* flag = (int*)d_ws;  // 4 bytes at ws[0..2)

  // workspace layout (bf16 elem offsets), lifetime-overlapped; total ~48 MB
  bf16* xb    = ws + 16;        // [16, 8388624)        convert_x -> gemm1
  bf16* wqkvT = ws + 8388624;   // [8388624, 14680080)  transposes -> gemm1
  bf16* qkv   = ws + 14680080;  // [14680080, 27262992) gemm1 -> rope/transposeV
  bf16* Qb    = ws + 16;        // reuse xb region      rope -> attn
  bf16* Kb    = ws + 8388624;   // reuse wqkvT region   rope -> attn
  bf16* Vtb   = ws + 10485776;  //                      transposeV -> attn
  bf16* woT   = ws + 12582928;  // [12582928, 16777232) transposeWo -> gemm2 (qkv dead)
  bf16* attno = ws + 16777232;  // [16777232, 25165840) attn -> gemm2

  dim3 tb(32, 8);
  detect_dtype<<<1, 256, 0, stream>>>((const unsigned*)x, flag);
  convert_x<<<4096, 256, 0, stream>>>(x, xb, flag, 1048576);
  // W^T staging (B^T layout for gemm_bt), with dtype-adaptive read
  transpose_cvt<<<dim3(64, 64, 1), tb, 0, stream>>>(Wq, wqkvT, 2048, 2048, 0, 0, flag);
  transpose_cvt<<<dim3(16, 64, 1), tb, 0, stream>>>(Wk, wqkvT + 2048 * 2048, 512, 2048, 0, 0, flag);
  transpose_cvt<<<dim3(16, 64, 1), tb, 0, stream>>>(Wv, wqkvT + 2560 * 2048, 512, 2048, 0, 0, flag);
  // qkv = x @ [Wq|Wk|Wv]  (bf16 out)
  gemm_bt<<<dim3(QKVW / BN, (B_ * S_) / BM), 256, 0, stream>>>(xb, wqkvT, qkv, B_ * S_, QKVW, D_, nullptr);
  // RoPE + scatter q,k
  rope_scatter<<<B_ * S_, 256, 0, stream>>>(qkv, Qb, Kb);
  // V^T: per b, (2048 s x 512 c) -> (512 c x 2048 s); input bf16
  transpose_cvt<<<dim3(16, 64, B_), tb, 0, stream>>>(qkv + 2560, Vtb, QKVW, S_,
                                                     (long)S_ * QKVW, (long)512 * S_, nullptr);
  // Wo^T (dtype-adaptive read); overwrites dead qkv region
  transpose_cvt<<<dim3(64, 64, 1), tb, 0, stream>>>(Wo, woT, 2048, 2048, 0, 0, flag);
  // attention
  attn_kernel<<<dim3(S_ / 64, H_, B_), 256, 0, stream>>>(Qb, Kb, Vtb, attno);
  // out = attno @ Wo  (output dtype per flag)
  gemm_bt<<<dim3(D_ / BN, (B_ * S_) / BM), 256, 0, stream>>>(attno, woT, d_out, B_ * S_, D_, D_, flag);
}